// Round 1
// baseline (390.903 us; speedup 1.0000x reference)
//
#include <hip/hip_runtime.h>

#define NN   8192
#define FIN  512
#define FOUT 64
#define KT   256

typedef __attribute__((ext_vector_type(8))) short short8;
typedef __attribute__((ext_vector_type(4))) float floatx4;

__device__ __forceinline__ unsigned f2bf_u(float f) {
  union { float f; unsigned u; } v; v.f = f;
  return (v.u + 0x7fffu + ((v.u >> 16) & 1u)) >> 16;  // RTNE bf16
}
__device__ __forceinline__ unsigned pack2(float a, float b) {
  return f2bf_u(a) | (f2bf_u(b) << 16);
}

union U8 { uint4 u; short8 s; };

// Kernel 1: h = inp @ W via bf16 MFMA.
// W^T staged to LDS ONCE; A fragments direct global->reg (2-deep prefetch);
// no barriers in the main loop. 512 blocks x 256 threads, 16 rows/block.
__global__ __launch_bounds__(256) void k1_gemm_h(
    const float* __restrict__ inp, const float* __restrict__ W,
    const float* __restrict__ a,
    float* __restrict__ f1, float* __restrict__ f2,
    unsigned short* __restrict__ hT)
{
  __shared__ unsigned short wt[64][520];  // W^T bf16, row stride 1040B = 65*16
  __shared__ float hsm[16][65];
  __shared__ float alds[2 * FOUT];

  const int tid   = threadIdx.x;
  const int rbase = blockIdx.x * 16;
  if (tid < 2 * FOUT) alds[tid] = a[tid];

  // one-shot W^T staging (W is [512][64] fp32, 8192 float4, coalesced)
  {
    const float4* Wv = (const float4*)W;
#pragma unroll
    for (int j = 0; j < 32; ++j) {
      const int i  = j * 256 + tid;
      const int k  = i >> 4;          // 0..511
      const int c4 = (i & 15) * 4;    // feature base
      float4 f = Wv[i];
      wt[c4 + 0][k] = (unsigned short)f2bf_u(f.x);
      wt[c4 + 1][k] = (unsigned short)f2bf_u(f.y);
      wt[c4 + 2][k] = (unsigned short)f2bf_u(f.z);
      wt[c4 + 3][k] = (unsigned short)f2bf_u(f.w);
    }
  }

  const int lane = tid & 63;
  const int wv   = tid >> 6;     // n-tile 0..3 (16 features each)
  const int l15  = lane & 15;
  const int q    = lane >> 4;

  const float* ap = inp + (size_t)(rbase + l15) * FIN + q * 8;

  float4 Ab[2][4];
#pragma unroll
  for (int b = 0; b < 2; ++b) {
    Ab[b][0] = *(const float4*)(ap + b * 64);
    Ab[b][1] = *(const float4*)(ap + b * 64 + 4);
    Ab[b][2] = *(const float4*)(ap + b * 64 + 32);
    Ab[b][3] = *(const float4*)(ap + b * 64 + 36);
  }

  floatx4 acc = {0.f, 0.f, 0.f, 0.f};
  __syncthreads();  // wt ready

#pragma unroll
  for (int t = 0; t < 8; ++t) {
    const int cur = t & 1;  // compile-time after unroll
    U8 c0, c1;
    c0.u = make_uint4(pack2(Ab[cur][0].x, Ab[cur][0].y), pack2(Ab[cur][0].z, Ab[cur][0].w),
                      pack2(Ab[cur][1].x, Ab[cur][1].y), pack2(Ab[cur][1].z, Ab[cur][1].w));
    c1.u = make_uint4(pack2(Ab[cur][2].x, Ab[cur][2].y), pack2(Ab[cur][2].z, Ab[cur][2].w),
                      pack2(Ab[cur][3].x, Ab[cur][3].y), pack2(Ab[cur][3].z, Ab[cur][3].w));
    if (t < 6) {  // prefetch tile t+2
      const float* an = ap + (t + 2) * 64;
      Ab[cur][0] = *(const float4*)(an);
      Ab[cur][1] = *(const float4*)(an + 4);
      Ab[cur][2] = *(const float4*)(an + 32);
      Ab[cur][3] = *(const float4*)(an + 36);
    }
    const unsigned short* wrow = &wt[wv * 16 + l15][t * 64 + q * 8];
    short8 b0 = *(const short8*)(wrow);        // ks=0
    short8 b1 = *(const short8*)(wrow + 32);   // ks=1
    acc = __builtin_amdgcn_mfma_f32_16x16x32_bf16(c0.s, b0, acc, 0, 0, 0);
    acc = __builtin_amdgcn_mfma_f32_16x16x32_bf16(c1.s, b1, acc, 0, 0, 0);
  }

  // epilogue: C layout col = lane&15 (feature), row = quad*4 + reg (node)
  const int m0 = q * 4;
  const int n  = wv * 16 + l15;
#pragma unroll
  for (int rg = 0; rg < 4; ++rg) hsm[m0 + rg][n] = acc[rg];
  *(uint2*)&hT[(size_t)n * NN + rbase + m0] =
      make_uint2(pack2(acc[0], acc[1]), pack2(acc[2], acc[3]));

  __syncthreads();
  if (tid < 16) {
    float s1 = 0.f, s2 = 0.f;
#pragma unroll 8
    for (int c = 0; c < FOUT; ++c) {
      float hv = hsm[tid][c];
      s1 += hv * alds[c];
      s2 += hv * alds[FOUT + c];
    }
    f1[rbase + tid] = s1;
    f2[rbase + tid] = s2;
  }
}

// Kernel 2: fused masked-softmax-weighted aggregation.
// KT=256, dbuf wlds, ONE raw barrier per iter (lgkmcnt-only wait: global
// prefetches stay in flight across it). hT B-fragments direct from L2 per
// wave (waves own disjoint 16-row slices -> no LDS staging, no extra traffic).
#define GAT_W4(FV, AV, P0, P1)                                              \
  { float e0 = f1v + FV.x; e0 = fmaxf(e0, 0.2f * e0);                       \
    float e1 = f1v + FV.y; e1 = fmaxf(e1, 0.2f * e1);                       \
    float e2 = f1v + FV.z; e2 = fmaxf(e2, 0.2f * e2);                       \
    float e3 = f1v + FV.w; e3 = fmaxf(e3, 0.2f * e3);                       \
    float x0 = AV.x ? __expf(e0) : 0.f;                                     \
    float x1 = AV.y ? __expf(e1) : 0.f;                                     \
    float x2 = AV.z ? __expf(e2) : 0.f;                                     \
    float x3 = AV.w ? __expf(e3) : 0.f;                                     \
    lsum += (x0 + x1) + (x2 + x3);                                          \
    P0 = pack2(x0, x1); P1 = pack2(x2, x3); }

#define K2_ITER(IT, ACUR, ANXT, BUF)                                        \
  {                                                                          \
    if ((IT) < 31) {  /* earliest-issue adj prefetch (HBM, latency-critical) */ \
      const int* apf = arow + ((IT) + 1) * KT;                               \
      ANXT[0] = *(const int4*)(apf);                                         \
      ANXT[1] = *(const int4*)(apf + 4);                                     \
      ANXT[2] = *(const int4*)(apf + 8);                                     \
      ANXT[3] = *(const int4*)(apf + 12);                                    \
    }                                                                        \
    unsigned p0, p1, p2, p3, p4, p5, p6, p7;                                 \
    GAT_W4(F[0], ACUR[0], p0, p1)                                            \
    GAT_W4(F[1], ACUR[1], p2, p3)                                            \
    GAT_W4(F[2], ACUR[2], p4, p5)                                            \
    GAT_W4(F[3], ACUR[3], p6, p7)                                            \
    *(uint4*)&wlds[BUF][r][c16]     = make_uint4(p0, p1, p2, p3);            \
    *(uint4*)&wlds[BUF][r][c16 + 8] = make_uint4(p4, p5, p6, p7);            \
    if ((IT) < 31) {  /* f2 is L1/L2-hot, late single-buffered reload */     \
      const float* fpf = frow + ((IT) + 1) * KT;                             \
      F[0] = *(const float4*)(fpf);                                          \
      F[1] = *(const float4*)(fpf + 4);                                      \
      F[2] = *(const float4*)(fpf + 8);                                      \
      F[3] = *(const float4*)(fpf + 12);                                     \
    }                                                                        \
    asm volatile("s_waitcnt lgkmcnt(0)" ::: "memory"); /* wlds visible */    \
    __builtin_amdgcn_s_barrier();      /* vmcnt NOT drained: loads fly on */ \
    _Pragma("unroll")                                                        \
    for (int ks = 0; ks < 8; ++ks) {                                         \
      short8 af = *(const short8*)&wlds[BUF][l15][ks * 32 + q * 8];          \
      acc = __builtin_amdgcn_mfma_f32_16x16x32_bf16(af, Hf[ks], acc, 0, 0, 0); \
    }                                                                        \
    if ((IT) < 31) {  /* hT fragments for next tile (L2-hot) */              \
      const unsigned short* hpf = hrow + ((IT) + 1) * KT;                    \
      _Pragma("unroll")                                                      \
      for (int ks = 0; ks < 8; ++ks) Hf[ks] = *(const short8*)(hpf + ks * 32); \
    }                                                                        \
  }

__global__ __launch_bounds__(256) void k2_attn(
    const int* __restrict__ adj,
    const float* __restrict__ f1g, const float* __restrict__ f2g,
    const unsigned short* __restrict__ hT,
    float* __restrict__ out)
{
  __shared__ unsigned short wlds[2][16][264];  // dbuf; row stride 528B = 33*16
  __shared__ float lred[16][17];
  __shared__ float linv_s[16];

  const int tid   = threadIdx.x;
  const int rbase = blockIdx.x * 16;
  const int lane  = tid & 63;
  const int wv    = tid >> 6;
  const int l15   = lane & 15;
  const int q     = lane >> 4;

  const int r   = tid >> 4;           // 0..15 attention row
  const int c16 = (tid & 15) * 16;    // 16 cols per thread within KT
  const float f1v = f1g[rbase + r];
  const int* arow   = adj + (size_t)(rbase + r) * NN + c16;
  const float* frow = f2g + c16;
  const unsigned short* hrow = hT + (size_t)(wv * 16 + l15) * NN + q * 8;

  floatx4 acc = {0.f, 0.f, 0.f, 0.f};
  float lsum = 0.f;

  int4 Aa[4], Az[4];
  float4 F[4];
  short8 Hf[8];

  // prologue: tile 0
  Aa[0] = *(const int4*)(arow);
  Aa[1] = *(const int4*)(arow + 4);
  Aa[2] = *(const int4*)(arow + 8);
  Aa[3] = *(const int4*)(arow + 12);
  F[0] = *(const float4*)(frow);
  F[1] = *(const float4*)(frow + 4);
  F[2] = *(const float4*)(frow + 8);
  F[3] = *(const float4*)(frow + 12);
#pragma unroll
  for (int ks = 0; ks < 8; ++ks) Hf[ks] = *(const short8*)(hrow + ks * 32);

  for (int it = 0; it < 32; it += 2) {
    K2_ITER(it,     Aa, Az, 0)
    K2_ITER(it + 1, Az, Aa, 1)
  }

  // row-sum reduction (16 partials per row)
  lred[r][tid & 15] = lsum;
  __syncthreads();
  if (tid < 16) {
    float s = 0.f;
#pragma unroll
    for (int i = 0; i < 16; ++i) s += lred[tid][i];
    linv_s[tid] = 1.f / s;
  }
  __syncthreads();

  // epilogue: normalize + ELU; C layout col = lane&15, row = quad*4 + reg
  const int m0 = q * 4;
  const int n2 = wv * 16 + l15;
#pragma unroll
  for (int rg = 0; rg < 4; ++rg) {
    float v = acc[rg] * linv_s[m0 + rg];
    v = (v > 0.f) ? v : (__expf(v) - 1.f);
    out[(size_t)(rbase + m0 + rg) * FOUT + n2] = v;
  }
}

extern "C" void kernel_launch(void* const* d_in, const int* in_sizes, int n_in,
                              void* d_out, int out_size, void* d_ws, size_t ws_size,
                              hipStream_t stream) {
  (void)in_sizes; (void)n_in; (void)out_size; (void)ws_size;
  const float* inp = (const float*)d_in[0];
  const int*   adj = (const int*)d_in[1];
  const float* W   = (const float*)d_in[2];
  const float* a   = (const float*)d_in[3];
  float* out = (float*)d_out;

  float* f1 = (float*)d_ws;                        // 8192 fp32
  float* f2 = f1 + NN;                             // 8192 fp32
  unsigned short* hT = (unsigned short*)(f2 + NN); // 64*8192 bf16

  k1_gemm_h<<<NN / 16, 256, 0, stream>>>(inp, W, a, f1, f2, hT);
  k2_attn<<<NN / 16, 256, 0, stream>>>(adj, f1, f2, hT, out);
}